// Round 7
// baseline (27.828 us; speedup 1.0000x reference)
//
#include <hip/hip_runtime.h>

// RoI max-pool via channel-last transpose; whole-row compile-time pooling
// with 2-deep y software pipeline and one p-row per wave.
// features [4,256,38,38] f32, rois [512,5] f32, out [512,256,7,7] f32.

#define NROIS 512
#define CCH   256
#define FH    38
#define FW    38
#define HW    (FH * FW)          // 1444
#define SCALE 0.0625f
#define NEGF  (-3.402823466e+38f)

// ---------------- Kernel 1: transpose [4][256][1444] -> [4][1444][256] ----
__global__ __launch_bounds__(256) void transpose_kernel(
    const float* __restrict__ src, float* __restrict__ dst)
{
    __shared__ float tile[4][257];
    const int b  = blockIdx.y;
    const int s0 = blockIdx.x * 4;
    const int t  = threadIdx.x;                 // = channel

    const float4 v = *(const float4*)(src + ((size_t)(b * CCH + t)) * HW + s0);
    tile[0][t] = v.x; tile[1][t] = v.y; tile[2][t] = v.z; tile[3][t] = v.w;
    __syncthreads();

    const int s = t >> 6;                       // 0..3
    const int m = t & 63;
    float* drow = dst + ((size_t)b * HW + s0 + s) * CCH;
    #pragma unroll
    for (int k = 0; k < 4; ++k)
        drow[m + 64 * k] = tile[s][m + 64 * k];
}

// ---------------- Kernel 2: pooling ----------------
template <int WW>
__device__ __forceinline__ void load_row(float (&v)[WW], const float* __restrict__ rb)
{
    #pragma unroll
    for (int j = 0; j < WW; ++j) v[j] = rb[j * CCH];
}

template <int WW>
__device__ __forceinline__ void consume_row(const float (&v)[WW], float (&acc)[7])
{
    #pragma unroll
    for (int q = 0; q < 7; ++q) {
        const int xs = (q * WW) / 7;            // const-folded after unroll
        const int xe = ((q + 1) * WW + 6) / 7;
        #pragma unroll
        for (int j = xs; j < xe; ++j)
            acc[q] = fmaxf(acc[q], v[j]);
    }
}

template <int WW>
__device__ __forceinline__ void pool_p_row(
    const float* __restrict__ rb0,   // first row base (incl cg+lane+x1)
    int h,                           // 1..6, wave-uniform
    float (&acc)[7])
{
    if constexpr (WW <= 18) {
        // 2-deep software pipeline; clamped row index -> duplicate rows,
        // harmless under max.
        float va[WW], vb[WW];
        load_row<WW>(va, rb0);
        for (int y = 0; y < h; y += 2) {
            const float* r1 = rb0 + (size_t)min(y + 1, h - 1) * (FW * CCH);
            load_row<WW>(vb, r1);
            consume_row<WW>(va, acc);
            const float* r2 = rb0 + (size_t)min(y + 2, h - 1) * (FW * CCH);
            load_row<WW>(va, r2);
            consume_row<WW>(vb, acc);
        }
    } else {
        const float* rb = rb0;
        for (int y = 0; y < h; ++y) {
            float v[WW];
            load_row<WW>(v, rb);
            consume_row<WW>(v, acc);
            rb += (size_t)FW * CCH;
        }
    }
}

template <int NB>
__device__ __forceinline__ void write_out(
    float* __restrict__ outb, const float (*__restrict__ sm)[65], int tid)
{
    // 64 channels x NB bins; out stride per channel is 49.
    #pragma unroll
    for (int flat = 0; flat < 64 * NB; flat += 256) {
        const int f = flat + tid;
        if (f < 64 * NB) {
            const int c = f / NB;               // compile-time magic div
            const int l = f - c * NB;
            outb[c * 49 + l] = sm[l][c];
        }
    }
}

__global__ __launch_bounds__(256) void roipool_kernel(
    const float* __restrict__ featT,
    const float* __restrict__ rois,
    float* __restrict__ out)
{
    __shared__ float smem[28][65];

    const int n    = blockIdx.y;
    const int cg   = blockIdx.x * 64;
    const int ph   = blockIdx.z;               // 0: p 0-3, 1: p 4-6
    const int tid  = threadIdx.x;
    const int wv   = __builtin_amdgcn_readfirstlane(tid >> 6);
    const int lane = tid & 63;
    const int p    = wv + 4 * ph;

    // ROI decode (uniform per block)
    const float* r = rois + n * 5;
    const int b = (int)r[0];
    int x1 = (int)(r[1] * SCALE);
    int y1 = (int)(r[2] * SCALE);
    int x2 = (int)(r[3] * SCALE);
    int y2 = (int)(r[4] * SCALE);
    x1 = min(max(x1, 0), FW - 1);
    y1 = min(max(y1, 0), FH - 1);
    x2 = min(max(x2, 0), FW - 1);
    y2 = min(max(y2, 0), FH - 1);
    const int hh = y2 - y1 + 1;
    const int ww = x2 - x1 + 1;   // 1..38, uniform for whole block

    if (p < 7) {
        const int ys = y1 + (p * hh) / 7;
        const int h  = (y1 + ((p + 1) * hh + 6) / 7) - ys;

        const float* rb0 = featT + (size_t)b * HW * CCH + cg + lane
                         + (size_t)(ys * FW + x1) * CCH;

        float acc[7];
        #pragma unroll
        for (int q = 0; q < 7; ++q) acc[q] = NEGF;

        switch (ww) {
            case  1: pool_p_row< 1>(rb0, h, acc); break;
            case  2: pool_p_row< 2>(rb0, h, acc); break;
            case  3: pool_p_row< 3>(rb0, h, acc); break;
            case  4: pool_p_row< 4>(rb0, h, acc); break;
            case  5: pool_p_row< 5>(rb0, h, acc); break;
            case  6: pool_p_row< 6>(rb0, h, acc); break;
            case  7: pool_p_row< 7>(rb0, h, acc); break;
            case  8: pool_p_row< 8>(rb0, h, acc); break;
            case  9: pool_p_row< 9>(rb0, h, acc); break;
            case 10: pool_p_row<10>(rb0, h, acc); break;
            case 11: pool_p_row<11>(rb0, h, acc); break;
            case 12: pool_p_row<12>(rb0, h, acc); break;
            case 13: pool_p_row<13>(rb0, h, acc); break;
            case 14: pool_p_row<14>(rb0, h, acc); break;
            case 15: pool_p_row<15>(rb0, h, acc); break;
            case 16: pool_p_row<16>(rb0, h, acc); break;
            case 17: pool_p_row<17>(rb0, h, acc); break;
            case 18: pool_p_row<18>(rb0, h, acc); break;
            case 19: pool_p_row<19>(rb0, h, acc); break;
            case 20: pool_p_row<20>(rb0, h, acc); break;
            case 21: pool_p_row<21>(rb0, h, acc); break;
            case 22: pool_p_row<22>(rb0, h, acc); break;
            case 23: pool_p_row<23>(rb0, h, acc); break;
            case 24: pool_p_row<24>(rb0, h, acc); break;
            case 25: pool_p_row<25>(rb0, h, acc); break;
            case 26: pool_p_row<26>(rb0, h, acc); break;
            case 27: pool_p_row<27>(rb0, h, acc); break;
            case 28: pool_p_row<28>(rb0, h, acc); break;
            case 29: pool_p_row<29>(rb0, h, acc); break;
            case 30: pool_p_row<30>(rb0, h, acc); break;
            case 31: pool_p_row<31>(rb0, h, acc); break;
            case 32: pool_p_row<32>(rb0, h, acc); break;
            case 33: pool_p_row<33>(rb0, h, acc); break;
            case 34: pool_p_row<34>(rb0, h, acc); break;
            case 35: pool_p_row<35>(rb0, h, acc); break;
            case 36: pool_p_row<36>(rb0, h, acc); break;
            case 37: pool_p_row<37>(rb0, h, acc); break;
            default: pool_p_row<38>(rb0, h, acc); break;
        }

        #pragma unroll
        for (int q = 0; q < 7; ++q)
            smem[wv * 7 + q][lane] = acc[q];
    }
    __syncthreads();

    float* outb = out + (size_t)n * (CCH * 49) + (size_t)cg * 49 + ph * 28;
    if (ph == 0) write_out<28>(outb, smem, tid);
    else         write_out<21>(outb, smem, tid);
}

// ---------------- Fallback (ws too small) ----------------
__global__ __launch_bounds__(256) void roipool_fallback(
    const float* __restrict__ feat,
    const float* __restrict__ rois,
    float* __restrict__ out)
{
    int idx = blockIdx.x * blockDim.x + threadIdx.x;
    int q = idx % 7;
    int t = idx / 7;
    int p = t % 7;
    t /= 7;
    int c = t % CCH;
    int n = t / CCH;

    const float* r = rois + n * 5;
    int b  = (int)r[0];
    int x1 = (int)(r[1] * SCALE);
    int y1 = (int)(r[2] * SCALE);
    int x2 = (int)(r[3] * SCALE);
    int y2 = (int)(r[4] * SCALE);
    x1 = min(max(x1, 0), FW - 1);
    y1 = min(max(y1, 0), FH - 1);
    x2 = min(max(x2, 0), FW - 1);
    y2 = min(max(y2, 0), FH - 1);
    int hh = y2 - y1 + 1, ww = x2 - x1 + 1;

    int ys = y1 + (p * hh) / 7, ye = y1 + ((p + 1) * hh + 6) / 7;
    int xs = x1 + (q * ww) / 7, xe = x1 + ((q + 1) * ww + 6) / 7;

    const float* base = feat + ((size_t)b * CCH + c) * HW;
    float m = NEGF;
    for (int y = ys; y < ye; ++y)
        for (int x = xs; x < xe; ++x)
            m = fmaxf(m, base[y * FW + x]);
    out[idx] = m;
}

extern "C" void kernel_launch(void* const* d_in, const int* in_sizes, int n_in,
                              void* d_out, int out_size, void* d_ws, size_t ws_size,
                              hipStream_t stream) {
    const float* feat = (const float*)d_in[0];
    const float* rois = (const float*)d_in[1];
    float* out = (float*)d_out;

    const size_t need = (size_t)4 * HW * CCH * sizeof(float);   // 5.9 MB
    if (ws_size < need) {
        const int total = NROIS * CCH * 49;
        roipool_fallback<<<(total + 255) / 256, 256, 0, stream>>>(feat, rois, out);
        return;
    }

    float* featT = (float*)d_ws;

    dim3 tg(HW / 4, 4);                      // (361, 4)
    transpose_kernel<<<tg, 256, 0, stream>>>(feat, featT);

    dim3 pg(4, NROIS, 2);                    // cg x ROI x p-half
    roipool_kernel<<<pg, 256, 0, stream>>>(featT, rois, out);
}